// Round 3
// baseline (1364.299 us; speedup 1.0000x reference)
//
#include <hip/hip_runtime.h>
#include <cstddef>

#define NE 16384
#define NN 4096
#define BG 16

__device__ __forceinline__ float lrelu(float v){ return v >= 0.f ? v : 0.01f*v; }
__device__ __forceinline__ float sigm(float v){ return 1.f/(1.f + expf(-v)); }
__device__ __forceinline__ float rl(float v, int l){
    return __int_as_float(__builtin_amdgcn_readlane(__float_as_int(v), l));
}

// ---------------- setup: WihT, WhhT, h0, he, deg(dst), cnt(src), agg zero ----------------
__global__ __launch_bounds__(256) void setup_kernel(
    const float* __restrict__ x, const float* __restrict__ ea,
    const int* __restrict__ ei,
    const float* __restrict__ W0, const float* __restrict__ b0,
    const float* __restrict__ We1, const float* __restrict__ be1,
    const float* __restrict__ Whh, const float* __restrict__ Wih,
    float* __restrict__ WihT, float* __restrict__ WhhT,
    float* __restrict__ h, float* __restrict__ he,
    int* __restrict__ deg, int* __restrict__ cnt, float* __restrict__ agg)
{
    int t = blockIdx.x*256 + threadIdx.x;   // grid: 4096x256 = 1048576
    {   // he: [E,64]  lrelu(edge_attr @ We1 + be1)
        int e = t >> 6, f = t & 63;
        float v = be1[f];
        #pragma unroll
        for (int d = 0; d < 4; ++d) v += ea[e*4+d]*We1[d*64+f];
        he[t] = lrelu(v);
    }
    if (t < NN*64) {    // h0 = lrelu(x @ W0 + b0); also zero agg
        int n = t >> 6, f = t & 63;
        float v = b0[f];
        #pragma unroll
        for (int d = 0; d < 3; ++d) v += x[n*3+d]*W0[d*64+f];
        h[t] = lrelu(v);
        agg[t] = 0.f;
    }
    if (t < 12288) {
        int k = t / 192, g = t - k*192;
        WihT[t] = Wih[g*64 + k];   // WihT[k][g]
        WhhT[t] = Whh[g*64 + k];   // WhhT[k][g]
    }
    if (t < NE) {
        atomicAdd(&deg[ei[NE + t]], 1);   // in-degree (dst) for mean aggr
        atomicAdd(&cnt[ei[t]], 1);        // out-degree (src) for edge sort
    }
}

// ---------------- exclusive scan of cnt[4096] -> offs[4097] (1 block) ----------------
__global__ __launch_bounds__(256) void scan_kernel(const int* __restrict__ cnt,
                                                   int* __restrict__ offs)
{
    __shared__ int ps[256];
    int t = threadIdx.x;
    int base = t*16;
    int loc[16];
    int s = 0;
    #pragma unroll
    for (int i = 0; i < 16; ++i) { loc[i] = s; s += cnt[base+i]; }
    ps[t] = s; __syncthreads();
    for (int off = 1; off < 256; off <<= 1) {
        int v = 0;
        if (t >= off) v = ps[t-off];
        __syncthreads();
        if (t >= off) ps[t] += v;
        __syncthreads();
    }
    int pre = (t == 0) ? 0 : ps[t-1];
    #pragma unroll
    for (int i = 0; i < 16; ++i) offs[base+i] = pre + loc[i];
    if (t == 255) offs[NN] = pre + s;
}

// ---------------- scatter: build src-sorted edge arrays (dst + perm) ----------------
__global__ __launch_bounds__(256) void scatter_kernel(
    const int* __restrict__ ei, const int* __restrict__ offs,
    int* __restrict__ cnt,  // consumed as cursor via atomicSub
    int* __restrict__ dsts, int* __restrict__ perm)
{
    int e = blockIdx.x*256 + threadIdx.x;
    if (e >= NE) return;
    int s = ei[e], d = ei[NE + e];
    int old = atomicSub(&cnt[s], 1);
    int pos = offs[s] + old - 1;
    dsts[pos] = d; perm[pos] = e;
}

// ---------------- inv_deg + per-graph node ranges ----------------
__global__ __launch_bounds__(256) void inv_range_kernel(
    const int* __restrict__ deg, const int* __restrict__ batch,
    float* __restrict__ inv_deg, int* __restrict__ gstart, int* __restrict__ gend)
{
    int n = blockIdx.x*256 + threadIdx.x;
    if (n >= NN) return;
    inv_deg[n] = 1.f / fmaxf((float)deg[n], 1.f);
    int b  = batch[n];
    int bp = (n == 0)    ? -1 : batch[n-1];
    int bn = (n == NN-1) ? BG : batch[n+1];
    for (int g = bp+1; g <= b; ++g) gstart[g] = n;
    for (int g = b;   g <  bn; ++g) gend[g]   = n+1;
    if (n == 0)    for (int g = 0;   g < b;  ++g) gend[g]   = 0;
    if (n == NN-1) for (int g = b+1; g < BG; ++g) gstart[g] = NN;
}

// ---------------- fused G-GEMM + edge msg + scatter ----------------
// grid (256 node-groups, 2 k-halves), 512 threads = 8 waves.
// Wave w owns k = k0 + w*4 .. +3; thread acc[4][16] = G[n][k][lane] fragment.
// G never touches memory; h tile broadcast from registers via v_readlane.
__global__ __launch_bounds__(512) void fused_msg(
    const float* __restrict__ h, const float* __restrict__ We2,
    const float* __restrict__ be2, const float* __restrict__ he,
    const int* __restrict__ offs, const int* __restrict__ dsts,
    const int* __restrict__ perm, float* __restrict__ agg)
{
    __shared__ float tmp[8][4][64];   // per-wave partials for a 4-edge batch
    __shared__ float bias[16][64];
    int t = threadIdx.x;
    int lane = t & 63, w = t >> 6;
    int n0 = blockIdx.x * 16;
    int k0 = blockIdx.y * 32;
    int kb = k0 + w*4;

    // h tile in registers: h_reg[n] = h[n0+n][lane]  (all waves identical)
    float h_reg[16];
    #pragma unroll
    for (int n = 0; n < 16; ++n) h_reg[n] = h[(size_t)(n0+n)*64 + lane];

    // bias[n][f] = sum_d h[n,d]*be2[d*64+f]   (k-half 0 blocks only)
    if (blockIdx.y == 0) {
        #pragma unroll
        for (int p = 0; p < 2; ++p) {
            int idx = t + p*512;
            int n = idx >> 6;
            float acc_b = 0.f;
            for (int d = 0; d < 64; ++d)
                acc_b += rl(h_reg[n], d) * be2[d*64 + lane];
            bias[n][lane] = acc_b;
        }
    }

    // G fragment: acc[j][n] = sum_d h[n,d] * We2[kb+j][d*64+lane]
    float acc[4][16];
    #pragma unroll
    for (int j = 0; j < 4; ++j)
        #pragma unroll
        for (int n = 0; n < 16; ++n) acc[j][n] = 0.f;

    const float* wp = We2 + (size_t)kb*4096 + lane;
    #pragma unroll 4
    for (int d = 0; d < 64; ++d) {
        float a0 = wp[d*64];
        float a1 = wp[4096  + d*64];
        float a2 = wp[8192  + d*64];
        float a3 = wp[12288 + d*64];
        #pragma unroll
        for (int n = 0; n < 16; ++n) {
            float hv = rl(h_reg[n], d);
            acc[0][n] += hv*a0; acc[1][n] += hv*a1;
            acc[2][n] += hv*a2; acc[3][n] += hv*a3;
        }
    }
    __syncthreads();   // bias ready, tmp free

    // Edge phase: for each local node, contract he with the register G,
    // reduce the 8 k-slices across waves via LDS, flush one atomic per edge.
    #pragma unroll
    for (int n = 0; n < 16; ++n) {
        int a = offs[n0+n], b = offs[n0+n+1];
        for (int eb = a; eb < b; eb += 4) {
            int cnt4 = min(4, b-eb);
            for (int j2 = 0; j2 < cnt4; ++j2) {
                int pe = perm[eb+j2];
                const float* hep = he + (size_t)pe*64 + kb;
                float part = hep[0]*acc[0][n] + hep[1]*acc[1][n]
                           + hep[2]*acc[2][n] + hep[3]*acc[3][n];
                tmp[w][j2][lane] = part;
            }
            __syncthreads();
            if (w < cnt4) {
                int e = eb + w;
                float s = tmp[0][w][lane];
                #pragma unroll
                for (int ww = 1; ww < 8; ++ww) s += tmp[ww][w][lane];
                if (blockIdx.y == 0) s += bias[n][lane];
                atomicAdd(&agg[(size_t)dsts[e]*64 + lane], s);
            }
            __syncthreads();
        }
    }
}

// ---------------- node kernel: m -> gi GEMM -> GRU (in-place h); zeros agg ----
__global__ __launch_bounds__(256) void node_kernel(
    float* __restrict__ agg, const float* __restrict__ inv_deg,
    const float* __restrict__ conv_b, const float* __restrict__ root,
    const float* __restrict__ WhhT, const float* __restrict__ WihT,
    const float* __restrict__ bih, const float* __restrict__ bhh,
    float* __restrict__ h)
{
    __shared__ float WT[64][196];   // WihT[k][g]
    __shared__ float mT[64][18];    // m transposed [d][node]
    __shared__ float h_lds[16][64]; // old h tile
    int t = threadIdx.x;
    int n0 = blockIdx.x * 16;
    #pragma unroll
    for (int i = 0; i < 48; ++i) {  // stage WihT (12288)
        int idx = t + i*256;
        int k = idx / 192;
        WT[k][idx - k*192] = WihT[idx];
    }
    #pragma unroll
    for (int i = 0; i < 4; ++i) {   // stage h tile
        int idx = t + i*256;
        h_lds[idx>>6][idx&63] = h[(size_t)n0*64 + idx];
    }
    __syncthreads();

    #pragma unroll
    for (int i = 0; i < 4; ++i) {   // m = lrelu(agg*inv + h@root + conv_b); zero agg
        int idx = t + i*256;
        int n = idx >> 6, dd = idx & 63;
        int gn = n0 + n;
        float mr = 0.f;
        for (int d = 0; d < 64; ++d) mr += h_lds[n][d]*root[d*64 + dd];
        float av = agg[(size_t)gn*64 + dd];
        agg[(size_t)gn*64 + dd] = 0.f;   // ready for next iteration
        mT[dd][n] = lrelu(av*inv_deg[gn] + mr + conv_b[dd]);
    }
    __syncthreads();

    int tx = t & 31, ty = t >> 5;   // tx: gate pair, ty: node pair
    float acc[2][2][3] = {};
    for (int k = 0; k < 64; ++k) {
        float2 a  = *(float2*)&mT[k][ty*2];
        float2 br = *(float2*)&WT[k][tx*2];
        float2 bz = *(float2*)&WT[k][64 + tx*2];
        float2 bn = *(float2*)&WT[k][128 + tx*2];
        acc[0][0][0] += a.x*br.x; acc[0][1][0] += a.x*br.y;
        acc[1][0][0] += a.y*br.x; acc[1][1][0] += a.y*br.y;
        acc[0][0][1] += a.x*bz.x; acc[0][1][1] += a.x*bz.y;
        acc[1][0][1] += a.y*bz.x; acc[1][1][1] += a.y*bz.y;
        acc[0][0][2] += a.x*bn.x; acc[0][1][2] += a.x*bn.y;
        acc[1][0][2] += a.y*bn.x; acc[1][1][2] += a.y*bn.y;
    }

    #pragma unroll
    for (int j = 0; j < 2; ++j) {
        int g = tx*2 + j;
        #pragma unroll
        for (int i = 0; i < 2; ++i) {
            int n  = ty*2 + i;
            int gn = n0 + n;
            // gh = h_old @ Whh^T  (per gate), via pre-transposed WhhT[d][g]
            float ghr = bhh[g], ghz = bhh[64+g], ghn = bhh[128+g];
            for (int d = 0; d < 64; ++d) {
                float hv = h_lds[n][d];
                ghr += hv*WhhT[d*192 + g];
                ghz += hv*WhhT[d*192 + 64 + g];
                ghn += hv*WhhT[d*192 + 128 + g];
            }
            float r  = sigm(acc[i][j][0] + bih[g]      + ghr);
            float z  = sigm(acc[i][j][1] + bih[64+g]   + ghz);
            float nn = tanhf(acc[i][j][2] + bih[128+g] + r*ghn);
            float ho = h_lds[n][g];
            h[(size_t)gn*64 + g] = (1.f - z)*nn + z*ho;
        }
    }
}

// ---------------- finale ----------------
__device__ __forceinline__ float q_val(const float* lbih, const float* lbhh, int g)
{
    float gi = lbih[g]     + lbhh[g];
    float gg = lbih[128+g] + lbhh[128+g];
    float go = lbih[192+g] + lbhh[192+g];
    return sigm(go)*tanhf(sigm(gi)*tanhf(gg));   // hl0=cl0=q_star0=0
}

__global__ __launch_bounds__(256) void e_kernel(
    const float* __restrict__ h, const float* __restrict__ lbih,
    const float* __restrict__ lbhh, float* __restrict__ e)
{
    __shared__ float qs[64];
    int t = threadIdx.x;
    if (t < 64) qs[t] = q_val(lbih, lbhh, t);
    __syncthreads();
    int w = t >> 6, f = t & 63;
    int n = blockIdx.x*4 + w;
    float p = h[(size_t)n*64 + f]*qs[f];
    #pragma unroll
    for (int off = 32; off; off >>= 1) p += __shfl_xor(p, off);
    if (f == 0) e[n] = p;
}

__global__ __launch_bounds__(1024) void pool_kernel(
    const float* __restrict__ h, float* __restrict__ e,
    const int* __restrict__ gstart, const int* __restrict__ gend,
    const float* __restrict__ lbih, const float* __restrict__ lbhh,
    const float* __restrict__ Wout, const float* __restrict__ bout,
    float* __restrict__ out)
{
    __shared__ float red[1024];
    __shared__ float rp[64];
    __shared__ float sval;
    int g = blockIdx.x, t = threadIdx.x;
    int s = gstart[g], en = gend[g];

    float mx = -1e30f;
    for (int n = s+t; n < en; n += 1024) mx = fmaxf(mx, e[n]);
    red[t] = mx; __syncthreads();
    for (int st = 512; st; st >>= 1) { if (t < st) red[t] = fmaxf(red[t], red[t+st]); __syncthreads(); }
    if (t == 0) sval = red[0];
    __syncthreads();
    float lmx = sval;
    __syncthreads();

    float sm = 0.f;
    for (int n = s+t; n < en; n += 1024) { float a = expf(e[n]-lmx); e[n] = a; sm += a; }
    red[t] = sm; __syncthreads();
    for (int st = 512; st; st >>= 1) { if (t < st) red[t] += red[t+st]; __syncthreads(); }
    if (t == 0) sval = (red[0] > 0.f) ? 1.f/red[0] : 0.f;
    __syncthreads();
    float inv_asum = sval;
    __syncthreads();

    int w = t >> 6, f = t & 63;
    float racc = 0.f;
    for (int n = s+w; n < en; n += 16) racc += e[n]*h[(size_t)n*64 + f];
    red[t] = racc; __syncthreads();
    if (w == 0) {
        float a = 0.f;
        #pragma unroll
        for (int i = 0; i < 16; ++i) a += red[i*64 + f];
        rp[f] = a*inv_asum;
    }
    __syncthreads();

    if (t < 64) {
        float qv = q_val(lbih, lbhh, t);
        float p0 = qv*Wout[t*2]   + rp[t]*Wout[(64+t)*2];
        float p1 = qv*Wout[t*2+1] + rp[t]*Wout[(64+t)*2+1];
        #pragma unroll
        for (int off = 32; off; off >>= 1) { p0 += __shfl_xor(p0, off); p1 += __shfl_xor(p1, off); }
        if (t == 0) { out[g*2] = p0 + bout[0]; out[g*2+1] = p1 + bout[1]; }
    }
}

extern "C" void kernel_launch(void* const* d_in, const int* in_sizes, int n_in,
                              void* d_out, int out_size, void* d_ws, size_t ws_size,
                              hipStream_t stream)
{
    const float* x      = (const float*)d_in[0];
    const float* ea     = (const float*)d_in[1];
    const int*   ei     = (const int*)  d_in[2];
    const int*   batch  = (const int*)  d_in[3];
    const float* W0     = (const float*)d_in[4];
    const float* b0     = (const float*)d_in[5];
    const float* We1    = (const float*)d_in[6];
    const float* be1    = (const float*)d_in[7];
    const float* We2    = (const float*)d_in[8];
    const float* be2    = (const float*)d_in[9];
    const float* root   = (const float*)d_in[10];
    const float* conv_b = (const float*)d_in[11];
    const float* Wih    = (const float*)d_in[12];
    const float* Whh    = (const float*)d_in[13];
    const float* bih    = (const float*)d_in[14];
    const float* bhh    = (const float*)d_in[15];
    const float* lbih   = (const float*)d_in[18];
    const float* lbhh   = (const float*)d_in[19];
    const float* Wout   = (const float*)d_in[20];
    const float* bout   = (const float*)d_in[21];
    float* out = (float*)d_out;

    float* W = (float*)d_ws;
    size_t off = 0;
    float* h       = W + off; off += (size_t)NN*64;
    float* he      = W + off; off += (size_t)NE*64;
    float* agg     = W + off; off += (size_t)NN*64;
    float* WihT    = W + off; off += 12288;
    float* WhhT    = W + off; off += 12288;
    float* inv_deg = W + off; off += NN;
    float* e       = W + off; off += NN;
    int*   deg     = (int*)(W + off); off += NN;   // deg+cnt contiguous: one memset
    int*   cnt     = (int*)(W + off); off += NN;
    int*   offs    = (int*)(W + off); off += NN+1;
    int*   dsts    = (int*)(W + off); off += NE;
    int*   perm    = (int*)(W + off); off += NE;
    int*   gstart  = (int*)(W + off); off += BG;
    int*   gend    = (int*)(W + off); off += BG;

    hipMemsetAsync(deg, 0, 2*NN*sizeof(int), stream);
    setup_kernel<<<4096, 256, 0, stream>>>(x, ea, ei, W0, b0, We1, be1,
                                           Whh, Wih, WihT, WhhT, h, he, deg, cnt, agg);
    scan_kernel<<<1, 256, 0, stream>>>(cnt, offs);
    scatter_kernel<<<64, 256, 0, stream>>>(ei, offs, cnt, dsts, perm);
    inv_range_kernel<<<16, 256, 0, stream>>>(deg, batch, inv_deg, gstart, gend);

    for (int it = 0; it < 6; ++it) {
        fused_msg<<<dim3(NN/16, 2), 512, 0, stream>>>(h, We2, be2, he, offs, dsts, perm, agg);
        node_kernel<<<NN/16, 256, 0, stream>>>(agg, inv_deg, conv_b, root, WhhT,
                                               WihT, bih, bhh, h);
    }

    e_kernel<<<NN/4, 256, 0, stream>>>(h, lbih, lbhh, e);
    pool_kernel<<<BG, 1024, 0, stream>>>(h, e, gstart, gend, lbih, lbhh, Wout, bout, out);
}